// Round 6
// baseline (100.687 us; speedup 1.0000x reference)
//
#include <hip/hip_runtime.h>

#define NSAMPLE 32
#define RADI 0.1f   // rx == ry == rz
#define QPW 2       // queries per wave in scan kernel
#define WPB 4       // waves per block

// Pre-pass: pack xyz (N,3) AoS -> float4 (x,y,z,0): one dwordx4 per point.
__global__ __launch_bounds__(256) void pack_xyz_kernel(
    const float* __restrict__ xyz, float4* __restrict__ xyz4, int N)
{
    const int i = blockIdx.x * blockDim.x + threadIdx.x;
    if (i < N) {
        float4 v;
        v.x = xyz[i * 3 + 0];
        v.y = xyz[i * 3 + 1];
        v.z = xyz[i * 3 + 2];
        v.w = 0.0f;
        xyz4[i] = v;
    }
}

// Scan: one wave handles QPW consecutive queries. 256 pts/chunk, A/B register
// double buffer, ballot+prefix ordered slot assignment, early exit when all
// QPW queries have NSAMPLE hits. FUSED=false: store idx to ws + cnt to out.
// FUSED=true: do the gather+store epilogue inline (ws-too-small fallback).
template <bool PACKED, bool FUSED>
__global__ __launch_bounds__(64 * WPB, 8) void scan_kernel(
    const float*  __restrict__ xyz,       // (N,3) AoS (!PACKED)
    const float4* __restrict__ xyz4,      // (N)    (PACKED)
    const int*    __restrict__ xyz_cnt,   // (B,)
    const float*  __restrict__ new_xyz,   // (M,3)
    const int*    __restrict__ new_cnt,   // (B,)
    const float*  __restrict__ features,  // (N,C) (FUSED only)
    int*   __restrict__ idx_ws,           // (M,NSAMPLE) (!FUSED)
    float* __restrict__ out_grouped,      // (M,C,NSAMPLE) (FUSED only)
    float* __restrict__ out_cnt,          // (M,)
    int B, int M, int C)
{
    const int wave = threadIdx.x >> 6;
    const int lane = threadIdx.x & 63;
    const int qbase = (blockIdx.x * WPB + wave) * QPW;
    if (qbase >= M) return;

    __shared__ int s_idx_all[WPB][QPW][NSAMPLE];
    int (*s_idx)[NSAMPLE] = s_idx_all[wave];
    (&s_idx[0][0])[lane] = 0;   // QPW*NSAMPLE = 64 slots: zero-init (safe gather)

    // ---- per-query batch info (B tiny; wave-uniform values) ----
    int   xs[QPW], nbq[QPW], fnd[QPW];
    float qx[QPW], qy[QPW], qz[QPW];
    #pragma unroll
    for (int qi = 0; qi < QPW; ++qi) {
        const int q = qbase + qi;
        if (q < M) {
            int xstart = 0, qacc = 0, b = 0;
            for (int i = 0; i < B; ++i) {
                const int cnt = new_cnt[i];
                if (q < qacc + cnt) { b = i; break; }
                qacc += cnt; xstart += xyz_cnt[i];
            }
            xs[qi] = xstart; nbq[qi] = xyz_cnt[b];
            qx[qi] = new_xyz[q * 3 + 0];
            qy[qi] = new_xyz[q * 3 + 1];
            qz[qi] = new_xyz[q * 3 + 2];
            fnd[qi] = 0;
        } else {
            xs[qi] = xs[0]; nbq[qi] = nbq[0];
            qx[qi] = qx[0]; qy[qi] = qy[0]; qz[qi] = qz[0];
            fnd[qi] = NSAMPLE;   // inactive: pretend done
        }
    }
    bool uniform = true;
    #pragma unroll
    for (int qi = 1; qi < QPW; ++qi)
        uniform = uniform && (xs[qi] == xs[0]) && (nbq[qi] == nbq[0]);

    const unsigned long long lt = (1ull << lane) - 1ull;

    auto load_pt = [&](const float4* xp4, const float* xp, int p) -> float4 {
        if (PACKED) return xp4[p];
        float4 v;
        v.x = xp[p * 3 + 0]; v.y = xp[p * 3 + 1]; v.z = xp[p * 3 + 2]; v.w = 0.f;
        return v;
    };
    auto test_group = [&](const float4& v, int gpidx, bool inb) {
        #pragma unroll
        for (int qi = 0; qi < QPW; ++qi) {
            if (fnd[qi] >= NSAMPLE) continue;   // scalar skip (fnd in SGPR)
            const float m3 = fmaxf(fmaxf(fabsf(qx[qi] - v.x),
                                         fabsf(qy[qi] - v.y)),
                                   fabsf(qz[qi] - v.z));
            const bool c = inb & (m3 < RADI);
            const unsigned long long m = __ballot(c);
            if (c) {
                const int slot = fnd[qi] + (int)__popcll(m & lt);
                if (slot < NSAMPLE) s_idx[qi][slot] = gpidx;
            }
            fnd[qi] += (int)__popcll(m);
        }
    };
    auto alldone = [&]() -> bool {
        bool d = true;
        #pragma unroll
        for (int qi = 0; qi < QPW; ++qi) d &= (fnd[qi] >= NSAMPLE);
        return d;
    };

    if (uniform) {
        const float4* __restrict__ xp4 = PACKED ? (xyz4 + xs[0]) : nullptr;
        const float*  __restrict__ xp  = PACKED ? nullptr : (xyz + (size_t)xs[0] * 3);
        const int nb    = nbq[0];
        const int nfull = nb & ~255;
        int base = 0;

        if (nfull > 0 && !alldone()) {
            float4 A[4], Bb[4];
            #pragma unroll
            for (int k = 0; k < 4; ++k) A[k] = load_pt(xp4, xp, k * 64 + lane);

            while (true) {
                int nxt = base + 256;
                if (nxt < nfull) {
                    #pragma unroll
                    for (int k = 0; k < 4; ++k) Bb[k] = load_pt(xp4, xp, nxt + k * 64 + lane);
                }
                #pragma unroll
                for (int k = 0; k < 4; ++k)
                    test_group(A[k], xs[0] + base + k * 64 + lane, true);
                base = nxt;
                if (alldone() || base >= nfull) break;

                nxt = base + 256;
                if (nxt < nfull) {
                    #pragma unroll
                    for (int k = 0; k < 4; ++k) A[k] = load_pt(xp4, xp, nxt + k * 64 + lane);
                }
                #pragma unroll
                for (int k = 0; k < 4; ++k)
                    test_group(Bb[k], xs[0] + base + k * 64 + lane, true);
                base = nxt;
                if (alldone() || base >= nfull) break;
            }
        }
        while (!alldone() && base < nb) {   // masked tail
            #pragma unroll
            for (int k = 0; k < 4; ++k) {
                const int p = base + k * 64 + lane;
                const bool inb = (p < nb);
                const float4 v = load_pt(xp4, xp, inb ? p : 0);
                test_group(v, xs[0] + p, inb);
            }
            base += 256;
        }
    } else {
        // rare: queries span batches -> per-query masked loop
        #pragma unroll
        for (int qi = 0; qi < QPW; ++qi) {
            const float4* __restrict__ xp4 = PACKED ? (xyz4 + xs[qi]) : nullptr;
            const float*  __restrict__ xp  = PACKED ? nullptr : (xyz + (size_t)xs[qi] * 3);
            const int nb = nbq[qi];
            for (int base = 0; base < nb && fnd[qi] < NSAMPLE; base += 64) {
                const int p = base + lane;
                const bool inb = (p < nb);
                const float4 v = load_pt(xp4, xp, inb ? p : 0);
                const float m3 = fmaxf(fmaxf(fabsf(qx[qi] - v.x),
                                             fabsf(qy[qi] - v.y)),
                                       fabsf(qz[qi] - v.z));
                const bool c = inb & (m3 < RADI);
                const unsigned long long m = __ballot(c);
                if (c) {
                    const int slot = fnd[qi] + (int)__popcll(m & lt);
                    if (slot < NSAMPLE) s_idx[qi][slot] = xs[qi] + p;
                }
                fnd[qi] += (int)__popcll(m);
            }
        }
    }

    // lanes' ds_writes must land before cross-lane reads (single wave)
    asm volatile("s_waitcnt lgkmcnt(0)" ::: "memory");
    __builtin_amdgcn_sched_barrier(0);

    if (!FUSED) {
        // store indices (64 ints per wave, coalesced) + counts
        const int q_of_lane = qbase + (lane >> 5);
        if (q_of_lane < M)
            idx_ws[(size_t)qbase * NSAMPLE + lane] = (&s_idx[0][0])[lane];
        if (lane < QPW && (qbase + lane) < M) {
            int f = fnd[lane];
            out_cnt[qbase + lane] = (float)(f > NSAMPLE ? NSAMPLE : f);
        }
        return;
    }

    // ---- FUSED epilogue: direct gather + coalesced float4 stores ----
    const int s0  = 4 * (lane & 7);
    const int chi = lane >> 3;
    for (int qi = 0; qi < QPW; ++qi) {
        const int q = qbase + qi;
        if (q >= M) continue;
        const int found = fnd[qi] > NSAMPLE ? NSAMPLE : fnd[qi];
        const int r0 = s_idx[qi][s0 + 0];
        const int r1 = s_idx[qi][s0 + 1];
        const int r2 = s_idx[qi][s0 + 2];
        const int r3 = s_idx[qi][s0 + 3];
        const float k0 = (s0 + 0) < found ? 1.0f : 0.0f;
        const float k1 = (s0 + 1) < found ? 1.0f : 0.0f;
        const float k2 = (s0 + 2) < found ? 1.0f : 0.0f;
        const float k3 = (s0 + 3) < found ? 1.0f : 0.0f;
        const float* __restrict__ f0p = features + (size_t)r0 * C;
        const float* __restrict__ f1p = features + (size_t)r1 * C;
        const float* __restrict__ f2p = features + (size_t)r2 * C;
        const float* __restrict__ f3p = features + (size_t)r3 * C;
        float* __restrict__ og = out_grouped + (size_t)q * (C * NSAMPLE);
        #pragma unroll
        for (int k = 0; k < 8; ++k) {
            const int c = 8 * k + chi;
            float4 v;
            v.x = f0p[c] * k0;
            v.y = f1p[c] * k1;
            v.z = f2p[c] * k2;
            v.w = f3p[c] * k3;
            *reinterpret_cast<float4*>(og + (size_t)(k * 64 + lane) * 4) = v;
        }
        if (lane == 0) out_cnt[q] = (float)found;
    }
}

// Group: one wave per query; uniform, write-bound.
// lane owns rows s0..s0+3 (s0=4*(lane&7)) and channels c=8k+(lane>>3);
// store t0=(k*64+lane)*4 -> c=t0>>5, s=t0&31 matches (c, s0..s0+3).
__global__ __launch_bounds__(64 * WPB, 8) void group_kernel(
    const float* __restrict__ features,   // (N,C)
    const int*   __restrict__ idx_ws,     // (M,NSAMPLE)
    const float* __restrict__ out_cnt,    // (M,) written by scan_kernel
    float* __restrict__ out_grouped,      // (M,C,NSAMPLE)
    int M, int C)
{
    const int wave = threadIdx.x >> 6;
    const int lane = threadIdx.x & 63;
    const int q = blockIdx.x * WPB + wave;
    if (q >= M) return;

    const int found = (int)out_cnt[q];
    const int s0  = 4 * (lane & 7);
    const int chi = lane >> 3;
    const int4 r = *reinterpret_cast<const int4*>(idx_ws + (size_t)q * NSAMPLE + s0);
    const float k0 = (s0 + 0) < found ? 1.0f : 0.0f;
    const float k1 = (s0 + 1) < found ? 1.0f : 0.0f;
    const float k2 = (s0 + 2) < found ? 1.0f : 0.0f;
    const float k3 = (s0 + 3) < found ? 1.0f : 0.0f;

    const float* __restrict__ f0p = features + (size_t)r.x * C;
    const float* __restrict__ f1p = features + (size_t)r.y * C;
    const float* __restrict__ f2p = features + (size_t)r.z * C;
    const float* __restrict__ f3p = features + (size_t)r.w * C;

    float* __restrict__ og = out_grouped + (size_t)q * (C * NSAMPLE);
    #pragma unroll
    for (int k = 0; k < 8; ++k) {
        const int c = 8 * k + chi;
        float4 v;
        v.x = f0p[c] * k0;
        v.y = f1p[c] * k1;
        v.z = f2p[c] * k2;
        v.w = f3p[c] * k3;
        *reinterpret_cast<float4*>(og + (size_t)(k * 64 + lane) * 4) = v;
    }
}

extern "C" void kernel_launch(void* const* d_in, const int* in_sizes, int n_in,
                              void* d_out, int out_size, void* d_ws, size_t ws_size,
                              hipStream_t stream) {
    const float* xyz      = (const float*)d_in[0];
    const int*   xyz_cnt  = (const int*)d_in[1];
    const float* new_xyz  = (const float*)d_in[2];
    const int*   new_cnt  = (const int*)d_in[3];
    const float* features = (const float*)d_in[4];

    const int B = in_sizes[1];
    const int N = in_sizes[0] / 3;
    const int M = in_sizes[2] / 3;
    const int C = in_sizes[4] / N;   // 64

    float* out_grouped = (float*)d_out;
    float* out_cnt     = (float*)d_out + (size_t)M * C * NSAMPLE;

    const int qpb = WPB * QPW;  // 8 queries per scan block
    dim3 grid_s((M + qpb - 1) / qpb), grid_g((M + WPB - 1) / WPB), block(64 * WPB);

    const size_t pack_bytes = (size_t)N * sizeof(float4);
    const size_t idx_bytes  = (size_t)M * NSAMPLE * sizeof(int);

    if (ws_size >= pack_bytes + idx_bytes) {
        float4* xyz4  = (float4*)d_ws;                          // [0, N*16)
        int*    idx_w = (int*)((char*)d_ws + pack_bytes);       // [N*16, +M*128)
        hipLaunchKernelGGL(pack_xyz_kernel, dim3((N + 255) / 256), dim3(256), 0, stream,
                           xyz, xyz4, N);
        hipLaunchKernelGGL((scan_kernel<true, false>), grid_s, block, 0, stream,
                           xyz, (const float4*)xyz4, xyz_cnt, new_xyz, new_cnt,
                           features, idx_w, out_grouped, out_cnt, B, M, C);
        hipLaunchKernelGGL(group_kernel, grid_g, block, 0, stream,
                           features, idx_w, out_cnt, out_grouped, M, C);
    } else {
        hipLaunchKernelGGL((scan_kernel<false, true>), grid_s, block, 0, stream,
                           xyz, (const float4*)nullptr, xyz_cnt, new_xyz, new_cnt,
                           features, (int*)nullptr, out_grouped, out_cnt, B, M, C);
    }
}